// Round 7
// baseline (349.815 us; speedup 1.0000x reference)
//
#include <hip/hip_runtime.h>
#include <stdint.h>

// Problem dims (fixed by reference)
#define BB 4
#define SS 2048
#define EE 512
#define HH 1024
// token rows = 8192 (32 tiles of 256), ext rows = 2048 (8 tiles of 256)

typedef _Float16 f16;
typedef __attribute__((ext_vector_type(8))) _Float16 f16x8;
typedef __attribute__((ext_vector_type(4))) _Float16 f16x4;
typedef __attribute__((ext_vector_type(4))) float f32x4;

__device__ __forceinline__ void async16(void* lds, const void* g) {
  __builtin_amdgcn_global_load_lds(
      (const __attribute__((address_space(1))) unsigned int*)g,
      (__attribute__((address_space(3))) unsigned int*)lds, 16, 0, 0);
}

// ---------------------------------------------------------------------------
// 128x128 BT-GEMM core (4 waves / 256 threads) — used by score & pv.
// TERMS=1: acc += A*Bh; TERMS=2: + A*Bl; TERMS=3: Ah*Bh + Ah*Bl + Al*Bh.
// LDS XOR-swizzle: row r's 16B k-chunk c at position c ^ ((r>>1)&3):
// conflict-free ds_read_b128 (R2-verified: SQ_LDS_BANK_CONFLICT 1.2e7 -> 0).
// ---------------------------------------------------------------------------
template <int TERMS>
__device__ __forceinline__ void gemm_core(
    const f16* Ah, const f16* Al, const f16* Bh, const f16* Bl, int K, int ld,
    f16* lAh, f16* lAl, f16* lBh, f16* lBl, f32x4 acc[4][4]) {
  const int tid = threadIdx.x;
  const int wave = tid >> 6;
  const int lane = tid & 63;
  const int lrow = lane >> 2;
  const int lcol = (((lane & 3) ^ ((lane >> 3) & 3))) * 8;
  const int waveM = (wave >> 1) * 64;
  const int waveN = (wave & 1) * 64;
  const int frow = lane & 15;
  const int fk = ((lane >> 4) ^ ((frow >> 1) & 3)) * 8;

  for (int k0 = 0; k0 < K; k0 += 32) {
    __syncthreads();
#pragma unroll
    for (int i = 0; i < 2; ++i) {
      const int r0 = (wave * 2 + i) * 16;
      const size_t goff = (size_t)(r0 + lrow) * ld + (k0 + lcol);
      async16(&lAh[r0 * 32], Ah + goff);
      async16(&lBh[r0 * 32], Bh + goff);
      if (TERMS >= 2) async16(&lBl[r0 * 32], Bl + goff);
      if (TERMS >= 3) async16(&lAl[r0 * 32], Al + goff);
    }
    __syncthreads();

    f16x8 a[4], bh[4], bl[4], al[4];
#pragma unroll
    for (int i = 0; i < 4; ++i) {
      a[i] = *(const f16x8*)&lAh[(waveM + i * 16 + frow) * 32 + fk];
      bh[i] = *(const f16x8*)&lBh[(waveN + i * 16 + frow) * 32 + fk];
      if (TERMS >= 2) bl[i] = *(const f16x8*)&lBl[(waveN + i * 16 + frow) * 32 + fk];
      if (TERMS >= 3) al[i] = *(const f16x8*)&lAl[(waveM + i * 16 + frow) * 32 + fk];
    }
#pragma unroll
    for (int i = 0; i < 4; ++i)
#pragma unroll
      for (int j = 0; j < 4; ++j) {
        acc[i][j] = __builtin_amdgcn_mfma_f32_16x16x32_f16(a[i], bh[j], acc[i][j], 0, 0, 0);
        if (TERMS >= 2)
          acc[i][j] = __builtin_amdgcn_mfma_f32_16x16x32_f16(a[i], bl[j], acc[i][j], 0, 0, 0);
        if (TERMS >= 3)
          acc[i][j] = __builtin_amdgcn_mfma_f32_16x16x32_f16(al[i], bh[j], acc[i][j], 0, 0, 0);
      }
  }
}

// ---------------------------------------------------------------------------
// 256x128 BT-GEMM core (8 waves / 512 threads, wave grid 4x2). Same per-wave
// 64x64 job and swizzles as gemm_core, but staging per MFMA drops 750->500 B
// (A 16KB + Bhi/lo 16KB per iter for 2x the MFMA). R6 showed proj is
// staging-latency-bound, not HBM-bound.
// ---------------------------------------------------------------------------
template <int TERMS>
__device__ __forceinline__ void gemm_core256(
    const f16* A, const f16* Bh, const f16* Bl, int K, int ld,
    f16* lA, f16* lBh, f16* lBl, f32x4 acc[4][4]) {
  const int tid = threadIdx.x;
  const int wave = tid >> 6;  // 0..7
  const int lane = tid & 63;
  const int lrow = lane >> 2;
  const int lcol = (((lane & 3) ^ ((lane >> 3) & 3))) * 8;
  const int waveM = (wave >> 1) * 64;  // 0..192
  const int waveN = (wave & 1) * 64;
  const int frow = lane & 15;
  const int fk = ((lane >> 4) ^ ((frow >> 1) & 3)) * 8;

  for (int k0 = 0; k0 < K; k0 += 32) {
    __syncthreads();
    {
      const int r0 = wave * 16;  // A rows 0..127
      async16(&lA[r0 * 32], A + (size_t)(r0 + lrow) * ld + (k0 + lcol));
      const int r1 = 128 + wave * 16;  // A rows 128..255
      async16(&lA[r1 * 32], A + (size_t)(r1 + lrow) * ld + (k0 + lcol));
      async16(&lBh[r0 * 32], Bh + (size_t)(r0 + lrow) * ld + (k0 + lcol));
      if (TERMS >= 2)
        async16(&lBl[r0 * 32], Bl + (size_t)(r0 + lrow) * ld + (k0 + lcol));
    }
    __syncthreads();

    f16x8 a[4], bh[4], bl[4];
#pragma unroll
    for (int i = 0; i < 4; ++i) {
      a[i] = *(const f16x8*)&lA[(waveM + i * 16 + frow) * 32 + fk];
      bh[i] = *(const f16x8*)&lBh[(waveN + i * 16 + frow) * 32 + fk];
      if (TERMS >= 2) bl[i] = *(const f16x8*)&lBl[(waveN + i * 16 + frow) * 32 + fk];
    }
#pragma unroll
    for (int i = 0; i < 4; ++i)
#pragma unroll
      for (int j = 0; j < 4; ++j) {
        acc[i][j] = __builtin_amdgcn_mfma_f32_16x16x32_f16(a[i], bh[j], acc[i][j], 0, 0, 0);
        if (TERMS >= 2)
          acc[i][j] = __builtin_amdgcn_mfma_f32_16x16x32_f16(a[i], bl[j], acc[i][j], 0, 0, 0);
      }
  }
}

// Transposed epilogue for veT (256-row tile), in 2 row-halves x 2 col-halves.
// Fixes the 2B-stride-1KB scatter (R2/R3 write amp). tl: 64x136 f16 (17.4 KB).
// dst pre-offset to (bb*HH + h0)*EE + e0; tile covers e rows ge0..ge0+255.
__device__ __forceinline__ void epi_transposed256(
    f16* __restrict__ dst, const f32x4 acc[4][4], const float bias[4], f16* tl) {
  const int tid = threadIdx.x, wave = tid >> 6, lane = tid & 63;
  const int quad = lane >> 4, colIn16 = lane & 15;
  const int mq = wave >> 1;    // M quadrant 0..3
  const int half = mq >> 1;    // row half (128 rows)
  const int msub = mq & 1;     // 64-row sub within half
  const int np = wave & 1;     // col half owned
#pragma unroll
  for (int h = 0; h < 2; ++h) {
#pragma unroll
    for (int p = 0; p < 2; ++p) {
      __syncthreads();
      if (half == h && np == p) {
#pragma unroll
        for (int i = 0; i < 4; ++i)
#pragma unroll
          for (int j = 0; j < 4; ++j)
#pragma unroll
            for (int r = 0; r < 4; ++r) {
              const int rowL = msub * 64 + i * 16 + quad * 4 + r;  // 0..127
              const int colL = j * 16 + colIn16;                   // 0..63
              tl[colL * 136 + rowL] = (f16)(acc[i][j][r] + bias[j]);
            }
      }
      __syncthreads();
      for (int c = tid; c < 1024; c += 512) {
        const int colL = c >> 4, ch = c & 15;
        const f16x8 v = *(const f16x8*)&tl[colL * 136 + ch * 8];
        *(f16x8*)&dst[(size_t)(p * 64 + colL) * EE + h * 128 + ch * 8] = v;
      }
    }
  }
}

// fp32 -> fp16 cast, both inputs in one launch (hidden then ext)
__global__ __launch_bounds__(256) void cast_kernel(const float* __restrict__ xh32,
                                                   const float* __restrict__ xe32,
                                                   f16* __restrict__ xh,
                                                   f16* __restrict__ xe) {
  const int i = blockIdx.x * 256 + threadIdx.x;
  const int n4h = 8192 * HH / 4;
  const float* src = i < n4h ? xh32 : xe32;
  f16* dst = i < n4h ? xh : xe;
  const int k = i < n4h ? i : i - n4h;
  const float4 v = ((const float4*)src)[k];
  f16x4 o;
  o.x = (f16)v.x; o.y = (f16)v.y; o.z = (f16)v.z; o.w = (f16)v.w;
  ((f16x4*)dst)[k] = o;
}

// Transpose-split W: Wt[n'][k] = W_{n'>>10}[k][n'&1023], n' in [0,3072), fp16 hi+lo
__global__ void wsplit_kernel(const float* __restrict__ Wq, const float* __restrict__ Wk,
                              const float* __restrict__ Wv, f16* __restrict__ wt_hi,
                              f16* __restrict__ wt_lo) {
  __shared__ float tile[32][33];
  const int k0 = blockIdx.x * 32;
  const int n0g = blockIdx.y * 32;
  const int which = n0g >> 10;
  const float* W = which == 0 ? Wq : (which == 1 ? Wk : Wv);
  const int n0 = n0g & 1023;
  const int tx = threadIdx.x, ty = threadIdx.y;
#pragma unroll
  for (int i = 0; i < 32; i += 8)
    tile[ty + i][tx] = W[(size_t)(k0 + ty + i) * 1024 + n0 + tx];
  __syncthreads();
#pragma unroll
  for (int i = 0; i < 32; i += 8) {
    const int np = n0g + ty + i;
    const float v = tile[tx][ty + i];
    const size_t idx = (size_t)np * 1024 + k0 + tx;
    const f16 h = (f16)v;
    wt_hi[idx] = h;
    wt_lo[idx] = (f16)(v - (float)h);
  }
}

// ---------------------------------------------------------------------------
// Projection GEMM, 256x128 tiles, 512 threads. rows = [32 token | 8 ext]
// tiles of 256; cols = [q|k|v] (24 ntiles of 128).
// Split (B hi+lo): token-q, ext-k. Plain: token-k, all v.
// Per-XCD L2 window order (round-robin g%8 -> XCD, R6-verified):
// [ntile window of 2] x [XCD's mtiles] x [2]: A 2 MB + B 1 MB <= 4 MB L2.
// Grid 896: token 8x(12w x 4mt x 2) + ext 8x(8w x 1mt x 2).
// ---------------------------------------------------------------------------
__global__ __launch_bounds__(512, 4) void proj_kernel(
    const f16* __restrict__ xh, const f16* __restrict__ xe,
    const f16* __restrict__ wt_hi, const f16* __restrict__ wt_lo,
    const float* __restrict__ bq, const float* __restrict__ bk,
    const float* __restrict__ bv, f16* __restrict__ q_hi, f16* __restrict__ q_lo,
    f16* __restrict__ kt, f16* __restrict__ vt,
    f16* __restrict__ ke_hi, f16* __restrict__ ke_lo, f16* __restrict__ veT) {
  const int g = blockIdx.x;  // 0..895
  const int xcd = g & 7;
  const int s = g >> 3;      // 0..111
  int mtile, ntile;
  if (s < 96) {  // token tiles (mtile 0..31)
    const int w = s >> 3, r = s & 7;
    ntile = w * 2 + (r & 1);
    mtile = (r >> 1) * 8 + xcd;
  } else {  // ext tiles (mtile 32..39), no q
    const int s2 = s - 96;
    ntile = 8 + (s2 >> 1) * 2 + (s2 & 1);
    mtile = 32 + xcd;
  }
  const bool extRows = (mtile >= 32);

  __shared__ f16 lds[16384];  // 32 KB: A 8192 | Bh 4096 | Bl 4096; veT epi reuses

  const f16* A = extRows ? xe : xh;
  const int rowA = (extRows ? (mtile - 32) : mtile) * 256;
  const int rowB = ntile * 128;
  const bool split = (ntile < 8) || (extRows && ntile < 16);

  f32x4 acc[4][4];
#pragma unroll
  for (int i = 0; i < 4; ++i)
#pragma unroll
    for (int jj = 0; jj < 4; ++jj)
#pragma unroll
      for (int r = 0; r < 4; ++r) acc[i][jj][r] = 0.0f;

  if (split)
    gemm_core256<2>(A + (size_t)rowA * HH, wt_hi + (size_t)rowB * HH,
                    wt_lo + (size_t)rowB * HH, HH, HH,
                    lds, lds + 8192, lds + 12288, acc);
  else
    gemm_core256<1>(A + (size_t)rowA * HH, wt_hi + (size_t)rowB * HH, nullptr,
                    HH, HH, lds, lds + 8192, nullptr, acc);

  const int tid = threadIdx.x, wave = tid >> 6, lane = tid & 63;
  const int waveM = (wave >> 1) * 64, waveN = (wave & 1) * 64;
  const int colIn16 = lane & 15, rowQuad = (lane >> 4) * 4;
  float bias[4];
#pragma unroll
  for (int jj = 0; jj < 4; ++jj) {
    const int c = ntile * 128 + waveN + jj * 16 + colIn16;
    bias[jj] = c < 1024 ? bq[c] : (c < 2048 ? bk[c - 1024] : bv[c - 2048]);
  }

  if (extRows && ntile >= 16) {  // veT: transposed LDS epilogue
    const int ge0 = (mtile - 32) * 256;
    const int bb = ge0 >> 9, e0 = ge0 & 511;
    epi_transposed256(veT + ((size_t)bb * HH + (ntile - 16) * 128) * EE + e0,
                      acc, bias, lds);
    return;
  }

  // Scalar row-major epilogue (R3-proven; R4's full LDS repack regressed)
#pragma unroll
  for (int jj = 0; jj < 4; ++jj) {
    const int c = ntile * 128 + waveN + jj * 16 + colIn16;  // 0..3071
#pragma unroll
    for (int i = 0; i < 4; ++i) {
#pragma unroll
      for (int r = 0; r < 4; ++r) {
        const int lrowIdx = waveM + i * 16 + rowQuad + r;  // 0..255
        const float val = acc[i][jj][r] + bias[jj];
        if (c < 1024) {  // q (token rows only), hi+lo
          const size_t idx = (size_t)(mtile * 256 + lrowIdx) * HH + c;
          const f16 h = (f16)val;
          q_hi[idx] = h;
          q_lo[idx] = (f16)(val - (float)h);
        } else if (c < 2048) {  // k
          const int c2 = c - 1024;
          if (!extRows) {
            kt[(size_t)(mtile * 256 + lrowIdx) * HH + c2] = (f16)val;
          } else {
            const int ge = (mtile - 32) * 256 + lrowIdx;
            const size_t idx = (size_t)ge * HH + c2;
            const f16 h = (f16)val;
            ke_hi[idx] = h;
            ke_lo[idx] = (f16)(val - (float)h);
          }
        } else {  // v (token rows; ext handled above)
          vt[(size_t)(mtile * 256 + lrowIdx) * HH + (c - 2048)] = (f16)val;
        }
      }
    }
  }
}

// Score GEMM, full K=1024, 3-term: s_ext[b][s][e] = q[b,s,:] . k_ext[b,e,:]
// acc = qh*keh + qh*kel + ql*keh (dropped ql*kel ~1e-7 relative).
// Un-split-K (R7): halves s_part traffic, removes softmax partial add.
__global__ __launch_bounds__(256, 4) void score_kernel(
    const f16* __restrict__ q_hi, const f16* __restrict__ q_lo,
    const f16* __restrict__ ke_hi, const f16* __restrict__ ke_lo,
    float* __restrict__ s_ext) {
  const int b = blockIdx.z;
  const int mtile = blockIdx.y;  // 0..15
  const int ntile = blockIdx.x;  // 0..3
  __shared__ f16 lds[4 * 4096];
  const size_t aoff = ((size_t)b * SS + mtile * 128) * HH;
  const size_t boff = ((size_t)b * EE + ntile * 128) * HH;

  f32x4 acc[4][4];
#pragma unroll
  for (int i = 0; i < 4; ++i)
#pragma unroll
    for (int j = 0; j < 4; ++j)
#pragma unroll
      for (int r = 0; r < 4; ++r) acc[i][j][r] = 0.0f;

  gemm_core<3>(q_hi + aoff, q_lo + aoff, ke_hi + boff, ke_lo + boff, HH, HH,
               lds, lds + 4096, lds + 8192, lds + 12288, acc);

  const int tid = threadIdx.x, wave = tid >> 6, lane = tid & 63;
  const int waveM = (wave >> 1) * 64, waveN = (wave & 1) * 64;
  const int colIn16 = lane & 15, rowQuad = (lane >> 4) * 4;
#pragma unroll
  for (int j = 0; j < 4; ++j) {
    const int e = ntile * 128 + waveN + j * 16 + colIn16;
#pragma unroll
    for (int i = 0; i < 4; ++i)
#pragma unroll
      for (int r = 0; r < 4; ++r) {
        const int s = mtile * 128 + waveM + i * 16 + rowQuad + r;
        s_ext[((size_t)b * SS + s) * EE + e] = acc[i][j][r];
      }
  }
}

// Fused selfdot + softmax: s_self = q_hi.kt (q_lo term ~0.01 on one score,
// negligible after softmax); softmax over [s_self, s_ext row].
__global__ __launch_bounds__(256) void softmax_kernel(
    const f16* __restrict__ q_hi, const f16* __restrict__ kt,
    const float* __restrict__ s_ext, f16* __restrict__ probs,
    float* __restrict__ p_self) {
  const int t = blockIdx.x * 4 + (threadIdx.x >> 6);
  const int lane = threadIdx.x & 63;

  // selfdot
  const size_t base = (size_t)t * HH;
  float ss = 0.f;
#pragma unroll
  for (int it = 0; it < 2; ++it) {
    const int off = it * 512 + lane * 8;
    const f16x8 qh = *(const f16x8*)&q_hi[base + off];
    const f16x8 kh = *(const f16x8*)&kt[base + off];
#pragma unroll
    for (int u = 0; u < 8; ++u) ss += (float)qh[u] * (float)kh[u];
  }
#pragma unroll
  for (int m = 32; m > 0; m >>= 1) ss += __shfl_xor(ss, m, 64);

  // softmax over 1 + 512
  const float* r0 = s_ext + (size_t)t * EE;
  const float4 v0 = *(const float4*)&r0[lane * 4];
  const float4 v1 = *(const float4*)&r0[256 + lane * 4];
  float m = fmaxf(fmaxf(fmaxf(v0.x, v0.y), fmaxf(v0.z, v0.w)),
                  fmaxf(fmaxf(v1.x, v1.y), fmaxf(v1.z, v1.w)));
#pragma unroll
  for (int sh = 32; sh > 0; sh >>= 1) m = fmaxf(m, __shfl_xor(m, sh, 64));
  m = fmaxf(m, ss);
  const float e0 = __expf(v0.x - m), e1 = __expf(v0.y - m);
  const float e2 = __expf(v0.z - m), e3 = __expf(v0.w - m);
  const float e4 = __expf(v1.x - m), e5 = __expf(v1.y - m);
  const float e6 = __expf(v1.z - m), e7 = __expf(v1.w - m);
  float sum = ((e0 + e1) + (e2 + e3)) + ((e4 + e5) + (e6 + e7));
#pragma unroll
  for (int sh = 32; sh > 0; sh >>= 1) sum += __shfl_xor(sum, sh, 64);
  const float es = __expf(ss - m);
  const float inv = 1.0f / (sum + es);
  f16x4 p0, p1;
  p0.x = (f16)(e0 * inv); p0.y = (f16)(e1 * inv);
  p0.z = (f16)(e2 * inv); p0.w = (f16)(e3 * inv);
  p1.x = (f16)(e4 * inv); p1.y = (f16)(e5 * inv);
  p1.z = (f16)(e6 * inv); p1.w = (f16)(e7 * inv);
  *(f16x4*)&probs[(size_t)t * EE + lane * 4] = p0;
  *(f16x4*)&probs[(size_t)t * EE + 256 + lane * 4] = p1;
  if (lane == 0) p_self[t] = es * inv;
}

// PV GEMM per batch: out[b,s,h] = probs[b,s,:] . v_ext[b,:,h] + p_self*v_tok
__global__ __launch_bounds__(256, 4) void pv_kernel(
    const f16* __restrict__ probs, const f16* __restrict__ veT,
    const float* __restrict__ p_self, const f16* __restrict__ vt,
    float* __restrict__ out) {
  const int b = blockIdx.z;
  const int mtile = blockIdx.y;  // 0..15 (S)
  const int ntile = blockIdx.x;  // 0..7  (H)
  __shared__ f16 lds[2 * 4096];
  const size_t aoff = ((size_t)b * SS + mtile * 128) * EE;
  const size_t boff = ((size_t)b * HH + ntile * 128) * EE;

  f32x4 acc[4][4];
#pragma unroll
  for (int i = 0; i < 4; ++i)
#pragma unroll
    for (int j = 0; j < 4; ++j)
#pragma unroll
      for (int r = 0; r < 4; ++r) acc[i][j][r] = 0.0f;

  gemm_core<1>(probs + aoff, nullptr, veT + boff, nullptr, EE, EE,
               lds, nullptr, lds + 4096, nullptr, acc);

  const int tid = threadIdx.x, wave = tid >> 6, lane = tid & 63;
  const int waveM = (wave >> 1) * 64, waveN = (wave & 1) * 64;
  const int colIn16 = lane & 15, rowQuad = (lane >> 4) * 4;
#pragma unroll
  for (int j = 0; j < 4; ++j) {
    const int h = ntile * 128 + waveN + j * 16 + colIn16;
#pragma unroll
    for (int i = 0; i < 4; ++i)
#pragma unroll
      for (int r = 0; r < 4; ++r) {
        const int s = mtile * 128 + waveM + i * 16 + rowQuad + r;
        const size_t t = (size_t)b * SS + s;
        __builtin_nontemporal_store(
            acc[i][j][r] + p_self[t] * (float)vt[t * HH + h], &out[t * HH + h]);
      }
  }
}

extern "C" void kernel_launch(void* const* d_in, const int* in_sizes, int n_in,
                              void* d_out, int out_size, void* d_ws, size_t ws_size,
                              hipStream_t stream) {
  const float* hidden = (const float*)d_in[0];
  const float* ext    = (const float*)d_in[1];
  const float* Wq = (const float*)d_in[2];
  const float* bq = (const float*)d_in[3];
  const float* Wk = (const float*)d_in[4];
  const float* bk = (const float*)d_in[5];
  const float* Wv = (const float*)d_in[6];
  const float* bv = (const float*)d_in[7];
  float* out = (float*)d_out;

  char* ws = (char*)d_ws;
  size_t off = 0;
  auto alloc = [&](size_t bytes) {
    char* p = ws + off;
    off += (bytes + 255) & ~(size_t)255;
    return p;
  };
  const size_t TOK = 8192, EXT = 2048;
  f16* xh    = (f16*)alloc(TOK * HH * 2);
  f16* xe    = (f16*)alloc(EXT * HH * 2);
  f16* wt_hi = (f16*)alloc(3072ull * HH * 2);
  f16* wt_lo = (f16*)alloc(3072ull * HH * 2);
  f16* q_hi  = (f16*)alloc(TOK * HH * 2);
  f16* q_lo  = (f16*)alloc(TOK * HH * 2);
  f16* kt    = (f16*)alloc(TOK * HH * 2);
  f16* vt    = (f16*)alloc(TOK * HH * 2);
  f16* ke_hi = (f16*)alloc(EXT * HH * 2);
  f16* ke_lo = (f16*)alloc(EXT * HH * 2);
  f16* veT   = (f16*)alloc((size_t)BB * HH * EE * 2);
  float* p_self = (float*)alloc(TOK * 4);
  float* s_ext  = (float*)alloc((size_t)BB * SS * EE * 4);
  f16* probs    = (f16*)alloc((size_t)BB * SS * EE * 2);

  // 1. cast A-side inputs to fp16; transpose+split W hi/lo
  cast_kernel<<<10240, 256, 0, stream>>>(hidden, ext, xh, xe);
  wsplit_kernel<<<dim3(32, 96), dim3(32, 8), 0, stream>>>(Wq, Wk, Wv, wt_hi, wt_lo);

  // 2. fused projection GEMM (256x128 tiles, L2-window-ordered, 896 blocks)
  proj_kernel<<<896, 512, 0, stream>>>(
      xh, xe, wt_hi, wt_lo, bq, bk, bv,
      q_hi, q_lo, kt, vt, ke_hi, ke_lo, veT);

  // 3. attention
  score_kernel<<<dim3(4, 16, 4), 256, 0, stream>>>(q_hi, q_lo, ke_hi, ke_lo, s_ext);
  softmax_kernel<<<2048, 256, 0, stream>>>(q_hi, kt, s_ext, probs, p_self);
  pv_kernel<<<dim3(8, 16, 4), 256, 0, stream>>>(probs, veT, p_self, vt, out);
}